// Round 9
// baseline (473.163 us; speedup 1.0000x reference)
//
#include <hip/hip_runtime.h>

#define N_NODES 50000
#define N_EDGES 800000
#define IN_F 10
#define HID 256
#define EMB 128
#define BN_EPS 1e-5f
#define WCONV_ELEMS (4 * HID * HID + 2 * EMB * HID)  // 327680
#define WCONV_BLKS (WCONV_ELEMS / 256)       // 1280
#define IP_BLOCKS 1024
#define SSTRIDE 512
#define NSHARD 8
#define NPART 8
#define PART_SZ (N_NODES / NPART)            // 6250
#define SCAT_BLKS 2048
#define BCAP 64                               // fixed bucket capacity per node (max deg << 64)

typedef __attribute__((ext_vector_type(8))) short short8;
typedef __attribute__((ext_vector_type(4))) float floatx4;
typedef __attribute__((ext_vector_type(2))) float floatx2;

__device__ __forceinline__ unsigned short f2bf(float f) {
    unsigned u = __float_as_uint(f);
    unsigned r = (u + 0x7fffu + ((u >> 16) & 1u)) >> 16;
    return (unsigned short)r;
}
__device__ __forceinline__ float bf_lo(unsigned int u) { return __uint_as_float(u << 16); }
__device__ __forceinline__ float bf_hi(unsigned int u) { return __uint_as_float(u & 0xffff0000u); }
__device__ __forceinline__ float bf2f(unsigned short s) { return __uint_as_float(((unsigned)s) << 16); }

// async global->LDS 16B: linear LDS dest (wave-uniform base + lane*16)
__device__ __forceinline__ void gload_lds16(const unsigned short* g, unsigned short* l) {
    __builtin_amdgcn_global_load_lds(
        (const __attribute__((address_space(1))) unsigned int*)(uintptr_t)(const void*)g,
        (__attribute__((address_space(3))) unsigned int*)(unsigned int)(uintptr_t)(void*)l,
        16, 0, 0);
}

// ---------------- single-pass fixed-bucket scatter (XCD-partitioned) -------
// R8 lesson: do NOT fuse streaming work with this kernel -- atomics execute at
// the L2/coherence fabric and share capacity with ordinary traffic (fused ==
// serial sum). Keep it alone at full block count.
__global__ void k_scatter_bucket(const int* __restrict__ src, const int* __restrict__ dst,
                                 int* __restrict__ fill_pos, int* __restrict__ sorted_src) {
    int part = blockIdx.x & 7;
    int lo = part * PART_SZ, hi = lo + PART_SZ;
    int idx = (blockIdx.x >> 3) * 256 + threadIdx.x;  // 0..65535
    for (int e = idx; e < N_EDGES; e += (SCAT_BLKS / 8) * 256) {
        int d = dst[e];
        if (d >= lo && d < hi) {
            int p = atomicAdd(&fill_pos[d], 1);
            sorted_src[(size_t)d * BCAP + p] = src[e];
        }
    }
}

// -------- fused: weight convert/transpose + input projection --------
__global__ __launch_bounds__(256) void k_wconv_ip(
        const float* __restrict__ wl1, const float* __restrict__ wr1,
        const float* __restrict__ wl2, const float* __restrict__ wr2,
        const float* __restrict__ wl3, const float* __restrict__ wr3,
        unsigned short* __restrict__ wl1t, unsigned short* __restrict__ wr1t,
        unsigned short* __restrict__ wl2t, unsigned short* __restrict__ wr2t,
        unsigned short* __restrict__ wl3t, unsigned short* __restrict__ wr3t,
        const float* __restrict__ x, const float* __restrict__ w,
        const float* __restrict__ bias, unsigned short* __restrict__ h,
        float* __restrict__ stats) {
    __shared__ float sbuf[2048];
    __shared__ float qbuf[2048];
    int b = blockIdx.x;
    int t = threadIdx.x;
    if (b < WCONV_BLKS) {
        int idx = b * 256 + t;
        const int S = HID * HID;  // 65536
        if (idx < 4 * S) {
            int sel = idx >> 16;
            int o = idx & (S - 1);
            const float* wp = sel == 0 ? wl1 : sel == 1 ? wr1 : sel == 2 ? wl2 : wr2;
            unsigned short* wt = sel == 0 ? wl1t : sel == 1 ? wr1t : sel == 2 ? wl2t : wr2t;
            int n = o >> 8, k = o & 255;
            wt[o] = f2bf(wp[k * HID + n]);
        } else {
            int r = idx - 4 * S;
            int sel = r >> 15;
            int o = r & 32767;
            const float* wp = sel ? wr3 : wl3;
            unsigned short* wt = sel ? wr3t : wl3t;
            int n = o >> 8, k = o & 255;
            wt[o] = f2bf(wp[k * EMB + n]);
        }
        return;
    }
    // ---- input projection range ----
    int bb = b - WCONV_BLKS;
    int jg = t & 31;
    int ns = t >> 5;
    int j0 = jg * 8;

    float wreg[IN_F][8];
#pragma unroll
    for (int k = 0; k < IN_F; k++)
#pragma unroll
        for (int c = 0; c < 8; c++) wreg[k][c] = w[k * HID + j0 + c];
    float bj[8];
#pragma unroll
    for (int c = 0; c < 8; c++) bj[c] = bias[j0 + c];

    float s[8] = {}, q[8] = {};
    const int stride = IP_BLOCKS * 8;
    for (int base = bb * 8 + ns; base < N_NODES; base += stride) {
        float xr[IN_F];
#pragma unroll
        for (int k = 0; k < IN_F; k++) xr[k] = x[base * IN_F + k];
        float acc[8];
#pragma unroll
        for (int c = 0; c < 8; c++) {
            float a = bj[c];
#pragma unroll
            for (int k = 0; k < IN_F; k++) a += xr[k] * wreg[k][c];
            acc[c] = a;
            s[c] += a;
            q[c] += a * a;
        }
        uint4 o;
        o.x = (unsigned)f2bf(acc[0]) | ((unsigned)f2bf(acc[1]) << 16);
        o.y = (unsigned)f2bf(acc[2]) | ((unsigned)f2bf(acc[3]) << 16);
        o.z = (unsigned)f2bf(acc[4]) | ((unsigned)f2bf(acc[5]) << 16);
        o.w = (unsigned)f2bf(acc[6]) | ((unsigned)f2bf(acc[7]) << 16);
        ((uint4*)h)[(size_t)base * 32 + jg] = o;
    }

#pragma unroll
    for (int c = 0; c < 8; c++) {
        sbuf[ns * 256 + j0 + c] = s[c];
        qbuf[ns * 256 + j0 + c] = q[c];
    }
    __syncthreads();
    float ss = 0.f, qq = 0.f;
#pragma unroll
    for (int n2 = 0; n2 < 8; n2++) {
        ss += sbuf[n2 * 256 + t];
        qq += qbuf[n2 * 256 + t];
    }
    atomicAdd(&stats[t], ss);
    atomicAdd(&stats[256 + t], qq);
}

// ---------------- BN apply + ReLU + optional fp8 shadow --------
__global__ void k_bn_apply_relu(unsigned short* __restrict__ h, const float* __restrict__ stats,
                                const float* __restrict__ g, const float* __restrict__ b,
                                unsigned char* __restrict__ h8) {
    int idx = blockIdx.x * 256 + threadIdx.x;
    if (idx >= N_NODES * 32) return;
    int q = idx & 31;
    int j0 = q * 8;
    const float invn = 1.0f / (float)N_NODES;
    float sc[8], sh[8];
#pragma unroll
    for (int k = 0; k < 8; k++) {
        float ssum = 0.f, qsum = 0.f;
#pragma unroll
        for (int s = 0; s < NSHARD; s++) {
            ssum += stats[s * SSTRIDE + j0 + k];
            qsum += stats[s * SSTRIDE + 256 + j0 + k];
        }
        float mu = ssum * invn;
        float var = qsum * invn - mu * mu;
        float scale = g[j0 + k] * rsqrtf(var + BN_EPS);
        sc[k] = scale;
        sh[k] = b[j0 + k] - mu * scale;
    }
    uint4 v = ((uint4*)h)[idx];
    float f0 = fmaxf(bf_lo(v.x) * sc[0] + sh[0], 0.f);
    float f1 = fmaxf(bf_hi(v.x) * sc[1] + sh[1], 0.f);
    float f2 = fmaxf(bf_lo(v.y) * sc[2] + sh[2], 0.f);
    float f3 = fmaxf(bf_hi(v.y) * sc[3] + sh[3], 0.f);
    float f4 = fmaxf(bf_lo(v.z) * sc[4] + sh[4], 0.f);
    float f5 = fmaxf(bf_hi(v.z) * sc[5] + sh[5], 0.f);
    float f6 = fmaxf(bf_lo(v.w) * sc[6] + sh[6], 0.f);
    float f7 = fmaxf(bf_hi(v.w) * sc[7] + sh[7], 0.f);
    uint4 o;
    o.x = (unsigned)f2bf(f0) | ((unsigned)f2bf(f1) << 16);
    o.y = (unsigned)f2bf(f2) | ((unsigned)f2bf(f3) << 16);
    o.z = (unsigned)f2bf(f4) | ((unsigned)f2bf(f5) << 16);
    o.w = (unsigned)f2bf(f6) | ((unsigned)f2bf(f7) << 16);
    ((uint4*)h)[idx] = o;
    if (h8) {
        unsigned pa = __builtin_amdgcn_cvt_pk_fp8_f32(f0, f1, 0u, false);
        pa = __builtin_amdgcn_cvt_pk_fp8_f32(f2, f3, pa, true);
        unsigned pb = __builtin_amdgcn_cvt_pk_fp8_f32(f4, f5, 0u, false);
        pb = __builtin_amdgcn_cvt_pk_fp8_f32(f6, f7, pb, true);
        uint2 o8; o8.x = pa; o8.y = pb;
        ((uint2*)h8)[idx] = o8;
    }
}

// ---------------- fp8 neighbor mean aggregation: one node per 64-lane wave ------
__global__ void k_aggregate_fp8(const unsigned char* __restrict__ h8,
                                const int* __restrict__ deg,
                                const int* __restrict__ sorted_src,
                                unsigned short* __restrict__ agg) {
    int node = (blockIdx.x * blockDim.x + threadIdx.x) >> 6;
    int l = threadIdx.x & 63;
    int ec = l >> 4;        // edge slot 0..3
    int lane = l & 15;      // feature lane
    if (node >= N_NODES) return;
    int beg = node * BCAP;
    int d = deg[node];
    const uint4* h4 = (const uint4*)h8;
    float a[16] = {};
    for (int e = beg + ec; e < beg + d; e += 4) {
        int s = sorted_src[e];
        uint4 v = h4[(size_t)s * 16 + lane];
        floatx2 p;
        p = __builtin_amdgcn_cvt_pk_f32_fp8(v.x, false); a[0] += p.x;  a[1] += p.y;
        p = __builtin_amdgcn_cvt_pk_f32_fp8(v.x, true);  a[2] += p.x;  a[3] += p.y;
        p = __builtin_amdgcn_cvt_pk_f32_fp8(v.y, false); a[4] += p.x;  a[5] += p.y;
        p = __builtin_amdgcn_cvt_pk_f32_fp8(v.y, true);  a[6] += p.x;  a[7] += p.y;
        p = __builtin_amdgcn_cvt_pk_f32_fp8(v.z, false); a[8] += p.x;  a[9] += p.y;
        p = __builtin_amdgcn_cvt_pk_f32_fp8(v.z, true);  a[10] += p.x; a[11] += p.y;
        p = __builtin_amdgcn_cvt_pk_f32_fp8(v.w, false); a[12] += p.x; a[13] += p.y;
        p = __builtin_amdgcn_cvt_pk_f32_fp8(v.w, true);  a[14] += p.x; a[15] += p.y;
    }
#pragma unroll
    for (int i = 0; i < 16; i++) {
        a[i] += __shfl_xor(a[i], 32, 64);
        a[i] += __shfl_xor(a[i], 16, 64);
    }
    if (ec) return;
    float inv = 1.0f / (float)(d > 1 ? d : 1);
    uint4 o0, o1;
    o0.x = (unsigned)f2bf(a[0] * inv)  | ((unsigned)f2bf(a[1] * inv) << 16);
    o0.y = (unsigned)f2bf(a[2] * inv)  | ((unsigned)f2bf(a[3] * inv) << 16);
    o0.z = (unsigned)f2bf(a[4] * inv)  | ((unsigned)f2bf(a[5] * inv) << 16);
    o0.w = (unsigned)f2bf(a[6] * inv)  | ((unsigned)f2bf(a[7] * inv) << 16);
    o1.x = (unsigned)f2bf(a[8] * inv)  | ((unsigned)f2bf(a[9] * inv) << 16);
    o1.y = (unsigned)f2bf(a[10] * inv) | ((unsigned)f2bf(a[11] * inv) << 16);
    o1.z = (unsigned)f2bf(a[12] * inv) | ((unsigned)f2bf(a[13] * inv) << 16);
    o1.w = (unsigned)f2bf(a[14] * inv) | ((unsigned)f2bf(a[15] * inv) << 16);
    ((uint4*)agg)[(size_t)node * 32 + lane * 2] = o0;
    ((uint4*)agg)[(size_t)node * 32 + lane * 2 + 1] = o1;
}

// ---------------- bf16 aggregate-mean ADD into fp32 out: one node per wave ----------
__global__ void k_aggregate_add(const unsigned short* __restrict__ G,
                                const int* __restrict__ deg, const int* __restrict__ sorted_src,
                                float* __restrict__ out) {
    int node = (blockIdx.x * blockDim.x + threadIdx.x) >> 6;
    int l = threadIdx.x & 63;
    int ec = l >> 4;
    int lane = l & 15;
    if (node >= N_NODES) return;
    int beg = node * BCAP;
    int d = deg[node];
    const uint4* h4 = (const uint4*)G;
    float a0 = 0.f, a1 = 0.f, a2 = 0.f, a3 = 0.f, a4 = 0.f, a5 = 0.f, a6 = 0.f, a7 = 0.f;
    for (int e = beg + ec; e < beg + d; e += 4) {
        int s = sorted_src[e];
        uint4 v = h4[(size_t)s * 16 + lane];
        a0 += bf_lo(v.x); a1 += bf_hi(v.x);
        a2 += bf_lo(v.y); a3 += bf_hi(v.y);
        a4 += bf_lo(v.z); a5 += bf_hi(v.z);
        a6 += bf_lo(v.w); a7 += bf_hi(v.w);
    }
    float r[8] = {a0, a1, a2, a3, a4, a5, a6, a7};
#pragma unroll
    for (int i = 0; i < 8; i++) {
        r[i] += __shfl_xor(r[i], 32, 64);
        r[i] += __shfl_xor(r[i], 16, 64);
    }
    if (ec) return;
    float inv = 1.0f / (float)(d > 1 ? d : 1);
    float4* ob = (float4*)(out + (size_t)node * EMB + lane * 8);
    float4 p0 = ob[0], p1 = ob[1];
    p0.x += r[0] * inv; p0.y += r[1] * inv; p0.z += r[2] * inv; p0.w += r[3] * inv;
    p1.x += r[4] * inv; p1.y += r[5] * inv; p1.z += r[6] * inv; p1.w += r[7] * inv;
    ob[0] = p0; ob[1] = p1;
}

#define BK 64

// ---------------- dual-source bf16 MFMA GEMM v4 (layers 1,2) ----------
// 128x128 tile, 512 threads (8 waves). A via global_load_lds w16 into
// double-buffered swizzled LDS (v3 pipeline). B (L2-hot weights) loads
// DIRECTLY into registers one phase ahead: breg[parity][j][kc] holds
// B[n*HID + k0 + kc*32 + quad*8] -- byte-identical operands to the v3 LDS
// path (R1-verified mapping) -> bit-exact accumulation. Removes B's DMA and
// ds_reads; LDS 64->32KB. vmcnt invariant: entering phase ph, outstanding
// <= 6 (A(ph) 2 + B(ph) 4); issue A(ph+1)2 + B(ph+1)4 -> vmcnt(6) retires
// exactly A(ph)+B(ph), keeping the 6 newest in flight.
#define GEMM_BLKS 784

template <int NCOL, bool STATS>
__global__ __launch_bounds__(512, 4) void k_gemm_mfma(
        const unsigned short* __restrict__ A1, const unsigned short* __restrict__ B1t,
        const unsigned short* __restrict__ A2, const unsigned short* __restrict__ B2t,
        const float* __restrict__ bias, float* __restrict__ stats,
        unsigned short* __restrict__ Cout) {
    int b = blockIdx.x;
    int xcd = b & 7;
    int q = b >> 3;
    int cx = q & 1;
    int pr = (q >> 1) * 8 + xcd;
    int r0 = pr * 128;
    if (r0 >= N_NODES) return;
    int c0 = cx * 128;

    // per row: 64 k-shorts = 8 slots of 16B. phys slot ps holds logical k-slot
    // ls = ps ^ (row&7)  (involution -> same map on stage-source and read).
    __shared__ __attribute__((aligned(16))) unsigned short As[2][128 * 64];  // 2 x 16KB

    int t = threadIdx.x;
    int wave = t >> 6, lane = t & 63;
    int wm = wave >> 2, wn = wave & 3;
    int quad = lane >> 4, l15 = lane & 15;

    floatx4 acc[4][2];
#pragma unroll
    for (int i = 0; i < 4; i++)
#pragma unroll
        for (int j = 0; j < 2; j++) acc[i][j] = (floatx4){0.f, 0.f, 0.f, 0.f};

    short8 breg[2][2][2];  // [parity][j][kc]; k offset = kc*32 + quad*8 within BK=64

    auto stageA = [&](int buf, const unsigned short* __restrict__ A, int k0) {
#pragma unroll
        for (int it = 0; it < 2; it++) {
            int p = it * 512 + t;        // 0..1023 16B-slots
            int row = p >> 3, ps = p & 7;
            int ls = ps ^ (row & 7);
            int rr = r0 + row;
            if (rr >= N_NODES) rr = N_NODES - 1;  // junk; masked in epilogue
            gload_lds16(&A[(size_t)rr * HID + k0 + ls * 8], &As[buf][p * 8]);
        }
    };
    auto loadB = [&](int par, const unsigned short* __restrict__ B, int k0) {
#pragma unroll
        for (int j = 0; j < 2; j++) {
            int n = c0 + wn * 32 + j * 16 + l15;
#pragma unroll
            for (int kc = 0; kc < 2; kc++)
                breg[par][j][kc] = *(const short8*)&B[(size_t)n * HID + k0 + kc * 32 + quad * 8];
        }
    };

    stageA(0, A1, 0);     // A(0): 2 DMA
    loadB(0, B1t, 0);     // B(0): 4 reg loads   -> outstanding <= 6

    int cur = 0;
#pragma unroll
    for (int ph = 0; ph < 8; ph++) {
        if (ph < 7) {
            int np = ph + 1;
            stageA(cur ^ 1, (np >= 4) ? A2 : A1, (np & 3) * BK);        // +2
            loadB(np & 1, (np >= 4) ? B2t : B1t, (np & 3) * BK);        // +4
            // retire A(ph)+B(ph) (oldest 6 of <=12); keep the 6 newest in flight
            asm volatile("s_waitcnt vmcnt(6)\n\ts_barrier" ::: "memory");
        } else {
            asm volatile("s_waitcnt vmcnt(0)\n\ts_barrier" ::: "memory");
        }
#pragma unroll
        for (int kc = 0; kc < 2; kc++) {
            short8 a[4];
            int ls = kc * 4 + quad;
#pragma unroll
            for (int i = 0; i < 4; i++) {
                int arow = wm * 64 + i * 16 + l15;
                int ps = ls ^ (arow & 7);
                a[i] = *(const short8*)&As[cur][arow * 64 + ps * 8];
            }
            __builtin_amdgcn_s_setprio(1);
#pragma unroll
            for (int i = 0; i < 4; i++)
#pragma unroll
                for (int j = 0; j < 2; j++)
                    acc[i][j] = __builtin_amdgcn_mfma_f32_16x16x32_bf16(
                        a[i], breg[ph & 1][j][kc], acc[i][j], 0, 0, 0);
            __builtin_amdgcn_s_setprio(0);
        }
        // all waves' reads of As[cur] done before next phase's stage overwrites it
        asm volatile("s_barrier" ::: "memory");
        cur ^= 1;
    }

    float bv[2];
#pragma unroll
    for (int j = 0; j < 2; j++) bv[j] = bias[c0 + wn * 32 + j * 16 + l15];

    float s_part[2] = {0.f, 0.f};
    float q_part[2] = {0.f, 0.f};

#pragma unroll
    for (int i = 0; i < 4; i++) {
#pragma unroll
        for (int r = 0; r < 4; r++) {
            int m = r0 + wm * 64 + i * 16 + quad * 4 + r;
            if (m >= N_NODES) continue;
#pragma unroll
            for (int j = 0; j < 2; j++) {
                int n = c0 + wn * 32 + j * 16 + l15;
                float v = acc[i][j][r] + bv[j];
                if (STATS) { s_part[j] += v; q_part[j] += v * v; }
                Cout[(size_t)m * NCOL + n] = f2bf(v);
            }
        }
    }

    if (STATS) {
        float* sred = (float*)As;
        __syncthreads();
        if (t < 256) sred[t] = 0.f;
        __syncthreads();
#pragma unroll
        for (int j = 0; j < 2; j++) {
            int cl = wn * 32 + j * 16 + l15;
            atomicAdd(&sred[cl], s_part[j]);
            atomicAdd(&sred[128 + cl], q_part[j]);
        }
        __syncthreads();
        if (t < 128) {
            int base = (pr & (NSHARD - 1)) * SSTRIDE;
            atomicAdd(&stats[base + c0 + t], sred[t]);
            atomicAdd(&stats[base + 256 + c0 + t], sred[128 + t]);
        }
    }
}

// ---------------- layer-3 dual-OUTPUT GEMM v2: pipelined, fused 256-row B^T ----------
#define L3_BLKS 784

__global__ __launch_bounds__(512, 4) void k_gemm_l3_dual(
        const unsigned short* __restrict__ A, const unsigned short* __restrict__ Bt,
        const float* __restrict__ stats,
        const float* __restrict__ g, const float* __restrict__ be,
        const float* __restrict__ bl3, unsigned short* __restrict__ G,
        float* __restrict__ P) {
    int b = blockIdx.x;
    int xcd = b & 7;
    int q = b >> 3;
    int cx = q & 1;
    int pr = (q >> 1) * 8 + xcd;
    int r0 = pr * 128;
    if (r0 >= N_NODES) return;
    int c0 = cx * 128;

    __shared__ __attribute__((aligned(16))) unsigned short As[128 * 64];      // 16KB
    __shared__ __attribute__((aligned(16))) unsigned short Bs[2][128 * 64];   // 32KB
    __shared__ float scs[256], shs[256];

    int t = threadIdx.x;
    if (t < 256) {
        const float invn = 1.0f / (float)N_NODES;
        float ssum = 0.f, qsum = 0.f;
#pragma unroll
        for (int s = 0; s < NSHARD; s++) {
            ssum += stats[s * SSTRIDE + t];
            qsum += stats[s * SSTRIDE + 256 + t];
        }
        float mu = ssum * invn;
        float var = qsum * invn - mu * mu;
        float sc = g[t] * rsqrtf(var + BN_EPS);
        scs[t] = sc;
        shs[t] = be[t] - mu * sc;
    }
    __syncthreads();  // drains all vm; clean vmcnt baseline for the pipeline

    int wave = t >> 6, lane = t & 63;
    int wm = wave >> 2, wn = wave & 3;
    int quad = lane >> 4, l15 = lane & 15;

    floatx4 acc[4][2];
#pragma unroll
    for (int i = 0; i < 4; i++)
#pragma unroll
        for (int j = 0; j < 2; j++) acc[i][j] = (floatx4){0.f, 0.f, 0.f, 0.f};

    // thread's two staging slots (same for A and B paths)
    int p0_ = t, p1_ = 512 + t;
    int row0 = p0_ >> 3, ps0 = p0_ & 7, ls0 = ps0 ^ (row0 & 7);
    int row1 = p1_ >> 3, ps1 = p1_ & 7, ls1 = ps1 ^ (row1 & 7);
    int ar0 = r0 + row0; if (ar0 >= N_NODES) ar0 = N_NODES - 1;
    int ar1 = r0 + row1; if (ar1 >= N_NODES) ar1 = N_NODES - 1;

    auto stageB = [&](int buf, int k0) {
        gload_lds16(&Bt[(size_t)(c0 + row0) * HID + k0 + ls0 * 8], &Bs[buf][p0_ * 8]);
        gload_lds16(&Bt[(size_t)(c0 + row1) * HID + k0 + ls1 * 8], &Bs[buf][p1_ * 8]);
    };
    auto issueA = [&](int k0, uint4& v0, uint4& v1) {
        v0 = *(const uint4*)&A[(size_t)ar0 * HID + k0 + ls0 * 8];
        v1 = *(const uint4*)&A[(size_t)ar1 * HID + k0 + ls1 * 8];
    };
    auto xform = [&](uint4 vv, int cb) -> uint4 {
        float4 s0 = *(float4*)&scs[cb], s1 = *(float4*)&scs[cb + 4];
        float4 h0 = *(float4*)&shs[cb], h1 = *(float4*)&shs[cb + 4];
        float f0 = fmaxf(bf_lo(vv.x) * s0.x + h0.x, 0.f);
        float f1 = fmaxf(bf_hi(vv.x) * s0.y + h0.y, 0.f);
        float f2 = fmaxf(bf_lo(vv.y) * s0.z + h0.z, 0.f);
        float f3 = fmaxf(bf_hi(vv.y) * s0.w + h0.w, 0.f);
        float f4 = fmaxf(bf_lo(vv.z) * s1.x + h1.x, 0.f);
        float f5 = fmaxf(bf_hi(vv.z) * s1.y + h1.y, 0.f);
        float f6 = fmaxf(bf_lo(vv.w) * s1.z + h1.z, 0.f);
        float f7 = fmaxf(bf_hi(vv.w) * s1.w + h1.w, 0.f);
        uint4 ov;
        ov.x = (unsigned)f2bf(f0) | ((unsigned)f2bf(f1) << 16);
        ov.y = (unsigned)f2bf(f2) | ((unsigned)f2bf(f3) << 16);
        ov.z = (unsigned)f2bf(f4) | ((unsigned)f2bf(f5) << 16);
        ov.w = (unsigned)f2bf(f6) | ((unsigned)f2bf(f7) << 16);
        return ov;
    };

    uint4 va0, va1, vb0, vb1;
    stageB(0, 0);        // B(0): 2 DMA
    issueA(0, va0, va1); // A(0): 2 reg loads (order: B then A)

    int cur = 0;
#pragma unroll
    for (int ph = 0; ph < 4; ph++) {
        if (ph < 3) {
            stageB(cur ^ 1, (ph + 1) * BK);                    // B(ph+1): 2 DMA newest
            asm volatile("s_waitcnt vmcnt(2)" ::: "memory");   // drains B(ph), A(ph)
        } else {
            asm volatile("s_waitcnt vmcnt(0)" ::: "memory");
        }
        // transform A(ph) -> As (phys slots, XOR-swizzled logical source)
        *(uint4*)&As[p0_ * 8] = xform(va0, ph * BK + ls0 * 8);
        *(uint4*)&As[p1_ * 8] = xform(va1, ph * BK + ls1 * 8);
        asm volatile("s_waitcnt lgkmcnt(0)\n\ts_barrier" ::: "memory");
        if (ph < 3) issueA((ph + 1) * BK, vb0, vb1);  // hides under MFMA below
#pragma unroll
        for (int kc = 0; kc < 2; kc++) {
            short8 a[4], bfr[2];
            int ls = kc * 4 + quad;
#pragma unroll
            for (int i = 0; i < 4; i++) {
                int arow = wm * 64 + i * 16 + l15;
                int ps = ls ^ (arow & 7);
                a[i] = *(const short8*)&As[arow * 64 + ps * 8];
            }
#pragma unroll
            for (int j = 0; j < 2; j++) {
                int brow = wn * 32 + j * 16 + l15;
                int ps = ls ^ (brow & 7);
                bfr[j] = *(const short8*)&Bs[cur][brow * 64 + ps * 8];
            }
            __builtin_amdgcn_s_setprio(1);
#pragma unroll
            for (int i = 0; i < 4; i++)
#pragma unroll
                for (int j = 0; j < 2; j++)
                    acc[i][j] = __builtin_amdgcn_mfma_f32_16x16x32_bf16(a[i], bfr[j], acc[i][j], 0, 0, 0);
            __builtin_amdgcn_s_setprio(0);
        }
        asm volatile("s_barrier" ::: "memory");
        cur ^= 1;
        va0 = vb0; va1 = vb1;
    }

    float bv[2];
#pragma unroll
    for (int j = 0; j < 2; j++) bv[j] = bl3[wn * 32 + j * 16 + l15];

#pragma unroll
    for (int i = 0; i < 4; i++) {
#pragma unroll
        for (int r = 0; r < 4; r++) {
            int m = r0 + wm * 64 + i * 16 + quad * 4 + r;
            if (m >= N_NODES) continue;
#pragma unroll
            for (int j = 0; j < 2; j++) {
                int n = wn * 32 + j * 16 + l15;
                if (cx == 0) G[(size_t)m * EMB + n] = f2bf(acc[i][j][r]);
                else         P[(size_t)m * EMB + n] = acc[i][j][r] + bv[j];
            }
        }
    }
}

extern "C" void kernel_launch(void* const* d_in, const int* in_sizes, int n_in,
                              void* d_out, int out_size, void* d_ws, size_t ws_size,
                              hipStream_t stream) {
    const float* x    = (const float*)d_in[0];
    const int*   ei   = (const int*)d_in[1];
    const float* w_in = (const float*)d_in[2];
    const float* b_in = (const float*)d_in[3];
    const float* g_in = (const float*)d_in[4];
    const float* be_in= (const float*)d_in[5];
    const float* wl1  = (const float*)d_in[6];
    const float* bl1  = (const float*)d_in[7];
    const float* wr1  = (const float*)d_in[8];
    const float* g1   = (const float*)d_in[9];
    const float* be1  = (const float*)d_in[10];
    const float* wl2  = (const float*)d_in[11];
    const float* bl2  = (const float*)d_in[12];
    const float* wr2  = (const float*)d_in[13];
    const float* g2   = (const float*)d_in[14];
    const float* be2  = (const float*)d_in[15];
    const float* wl3  = (const float*)d_in[16];
    const float* bl3  = (const float*)d_in[17];
    const float* wr3  = (const float*)d_in[18];
    float* out = (float*)d_out;

    char* p = (char*)d_ws;
    auto alloc = [&](size_t bytes) -> void* {
        void* r = (void*)p;
        p += (bytes + 255) & ~(size_t)255;
        return r;
    };
    // zero-region: fill_pos + 3 sharded stats buffers (contiguous)
    int*   fill_pos = (int*)alloc((size_t)N_NODES * 4);
    float* stats0 = (float*)alloc((size_t)NSHARD * SSTRIDE * 4);
    float* stats1 = (float*)alloc((size_t)NSHARD * SSTRIDE * 4);
    float* stats2 = (float*)alloc((size_t)NSHARD * SSTRIDE * 4);
    size_t zlen = (size_t)((char*)stats2 + NSHARD * SSTRIDE * 4 - (char*)fill_pos);

    unsigned short* bufA = (unsigned short*)alloc((size_t)N_NODES * HID * 2);
    unsigned short* bufB = (unsigned short*)alloc((size_t)N_NODES * HID * 2);
    unsigned short* bufC = (unsigned short*)alloc((size_t)N_NODES * HID * 2);
    unsigned char*  h8   = (unsigned char*)alloc((size_t)N_NODES * HID);
    unsigned short* wl1t = (unsigned short*)alloc((size_t)HID * HID * 2);
    unsigned short* wr1t = (unsigned short*)alloc((size_t)HID * HID * 2);
    unsigned short* wl2t = (unsigned short*)alloc((size_t)HID * HID * 2);
    unsigned short* wr2t = (unsigned short*)alloc((size_t)HID * HID * 2);
    unsigned short* wl3t = (unsigned short*)alloc((size_t)EMB * HID * 2);  // contiguous with wr3t:
    unsigned short* wr3t = (unsigned short*)alloc((size_t)EMB * HID * 2);  // fused 256-row B^T for l3
    int*   sorted_src = (int*)alloc((size_t)N_NODES * BCAP * 4);           // 12.8 MB buckets
    (void)wr3t;

    const int* e_src = ei;
    const int* e_dst = ei + N_EDGES;

    hipMemsetAsync(fill_pos, 0, zlen, stream);
    k_scatter_bucket<<<SCAT_BLKS, 256, 0, stream>>>(e_src, e_dst, fill_pos, sorted_src);
    k_wconv_ip<<<WCONV_BLKS + IP_BLOCKS, 256, 0, stream>>>(
        wl1, wr1, wl2, wr2, wl3, wr3, wl1t, wr1t, wl2t, wr2t, wl3t, wr3t,
        x, w_in, b_in, bufA, stats0);
    k_bn_apply_relu<<<(N_NODES * 32 + 255) / 256, 256, 0, stream>>>(bufA, stats0, g_in, be_in, h8);

    int agg_blocks = ((size_t)N_NODES * 64 + 255) / 256;  // 12500

    // SAGE layer 1
    k_aggregate_fp8<<<agg_blocks, 256, 0, stream>>>(h8, fill_pos, sorted_src, bufC);
    k_gemm_mfma<HID, true><<<GEMM_BLKS, 512, 0, stream>>>(bufC, wl1t, bufA, wr1t, bl1, stats1, bufB);
    k_bn_apply_relu<<<(N_NODES * 32 + 255) / 256, 256, 0, stream>>>(bufB, stats1, g1, be1, h8);

    // SAGE layer 2 (raw h2 + stats2; BN deferred into layer-3 GEMM)
    k_aggregate_fp8<<<agg_blocks, 256, 0, stream>>>(h8, fill_pos, sorted_src, bufC);
    k_gemm_mfma<HID, true><<<GEMM_BLKS, 512, 0, stream>>>(bufC, wl2t, bufB, wr2t, bl2, stats2, bufA);

    // layer-3 dual GEMM with fused BN (fused B^T = wl3t||wr3t), then out += mean of G
    k_gemm_l3_dual<<<L3_BLKS, 512, 0, stream>>>(
        bufA, wl3t, stats2, g2, be2, bl3, bufB, out);
    k_aggregate_add<<<agg_blocks, 256, 0, stream>>>(bufB, fill_pos, sorted_src, out);
}

// Round 10
// 400.270 us; speedup vs baseline: 1.1821x; 1.1821x over previous
//
#include <hip/hip_runtime.h>

#define N_NODES 50000
#define N_EDGES 800000
#define IN_F 10
#define HID 256
#define EMB 128
#define BN_EPS 1e-5f
#define WCONV_ELEMS (4 * HID * HID + 2 * EMB * HID)  // 327680
#define WCONV_BLKS (WCONV_ELEMS / 256)       // 1280
#define IP_BLOCKS 1024
#define SSTRIDE 512
#define NSHARD 8
#define NPART 8
#define PART_SZ (N_NODES / NPART)            // 6250
#define SCAT_BLKS 2048
#define BCAP 64                               // fixed bucket capacity per node (max deg << 64)

typedef __attribute__((ext_vector_type(8))) short short8;
typedef __attribute__((ext_vector_type(4))) float floatx4;
typedef __attribute__((ext_vector_type(2))) float floatx2;

__device__ __forceinline__ unsigned short f2bf(float f) {
    unsigned u = __float_as_uint(f);
    unsigned r = (u + 0x7fffu + ((u >> 16) & 1u)) >> 16;
    return (unsigned short)r;
}
__device__ __forceinline__ float bf_lo(unsigned int u) { return __uint_as_float(u << 16); }
__device__ __forceinline__ float bf_hi(unsigned int u) { return __uint_as_float(u & 0xffff0000u); }
__device__ __forceinline__ float bf2f(unsigned short s) { return __uint_as_float(((unsigned)s) << 16); }

// async global->LDS 16B: linear LDS dest (wave-uniform base + lane*16)
__device__ __forceinline__ void gload_lds16(const unsigned short* g, unsigned short* l) {
    __builtin_amdgcn_global_load_lds(
        (const __attribute__((address_space(1))) unsigned int*)(uintptr_t)(const void*)g,
        (__attribute__((address_space(3))) unsigned int*)(unsigned int)(uintptr_t)(void*)l,
        16, 0, 0);
}

// ---------------- single-pass fixed-bucket scatter (XCD-partitioned) -------
// R8 lesson: do NOT fuse streaming work with this kernel -- atomics execute at
// the L2/coherence fabric and share capacity with ordinary traffic (fused ==
// serial sum). Keep it alone at full block count.
__global__ void k_scatter_bucket(const int* __restrict__ src, const int* __restrict__ dst,
                                 int* __restrict__ fill_pos, int* __restrict__ sorted_src) {
    int part = blockIdx.x & 7;
    int lo = part * PART_SZ, hi = lo + PART_SZ;
    int idx = (blockIdx.x >> 3) * 256 + threadIdx.x;  // 0..65535
    for (int e = idx; e < N_EDGES; e += (SCAT_BLKS / 8) * 256) {
        int d = dst[e];
        if (d >= lo && d < hi) {
            int p = atomicAdd(&fill_pos[d], 1);
            sorted_src[(size_t)d * BCAP + p] = src[e];
        }
    }
}

// -------- fused: weight convert/transpose + input projection --------
__global__ __launch_bounds__(256) void k_wconv_ip(
        const float* __restrict__ wl1, const float* __restrict__ wr1,
        const float* __restrict__ wl2, const float* __restrict__ wr2,
        const float* __restrict__ wl3, const float* __restrict__ wr3,
        unsigned short* __restrict__ wl1t, unsigned short* __restrict__ wr1t,
        unsigned short* __restrict__ wl2t, unsigned short* __restrict__ wr2t,
        unsigned short* __restrict__ wl3t, unsigned short* __restrict__ wr3t,
        const float* __restrict__ x, const float* __restrict__ w,
        const float* __restrict__ bias, unsigned short* __restrict__ h,
        float* __restrict__ stats) {
    __shared__ float sbuf[2048];
    __shared__ float qbuf[2048];
    int b = blockIdx.x;
    int t = threadIdx.x;
    if (b < WCONV_BLKS) {
        int idx = b * 256 + t;
        const int S = HID * HID;  // 65536
        if (idx < 4 * S) {
            int sel = idx >> 16;
            int o = idx & (S - 1);
            const float* wp = sel == 0 ? wl1 : sel == 1 ? wr1 : sel == 2 ? wl2 : wr2;
            unsigned short* wt = sel == 0 ? wl1t : sel == 1 ? wr1t : sel == 2 ? wl2t : wr2t;
            int n = o >> 8, k = o & 255;
            wt[o] = f2bf(wp[k * HID + n]);
        } else {
            int r = idx - 4 * S;
            int sel = r >> 15;
            int o = r & 32767;
            const float* wp = sel ? wr3 : wl3;
            unsigned short* wt = sel ? wr3t : wl3t;
            int n = o >> 8, k = o & 255;
            wt[o] = f2bf(wp[k * EMB + n]);
        }
        return;
    }
    // ---- input projection range ----
    int bb = b - WCONV_BLKS;
    int jg = t & 31;
    int ns = t >> 5;
    int j0 = jg * 8;

    float wreg[IN_F][8];
#pragma unroll
    for (int k = 0; k < IN_F; k++)
#pragma unroll
        for (int c = 0; c < 8; c++) wreg[k][c] = w[k * HID + j0 + c];
    float bj[8];
#pragma unroll
    for (int c = 0; c < 8; c++) bj[c] = bias[j0 + c];

    float s[8] = {}, q[8] = {};
    const int stride = IP_BLOCKS * 8;
    for (int base = bb * 8 + ns; base < N_NODES; base += stride) {
        float xr[IN_F];
#pragma unroll
        for (int k = 0; k < IN_F; k++) xr[k] = x[base * IN_F + k];
        float acc[8];
#pragma unroll
        for (int c = 0; c < 8; c++) {
            float a = bj[c];
#pragma unroll
            for (int k = 0; k < IN_F; k++) a += xr[k] * wreg[k][c];
            acc[c] = a;
            s[c] += a;
            q[c] += a * a;
        }
        uint4 o;
        o.x = (unsigned)f2bf(acc[0]) | ((unsigned)f2bf(acc[1]) << 16);
        o.y = (unsigned)f2bf(acc[2]) | ((unsigned)f2bf(acc[3]) << 16);
        o.z = (unsigned)f2bf(acc[4]) | ((unsigned)f2bf(acc[5]) << 16);
        o.w = (unsigned)f2bf(acc[6]) | ((unsigned)f2bf(acc[7]) << 16);
        ((uint4*)h)[(size_t)base * 32 + jg] = o;
    }

#pragma unroll
    for (int c = 0; c < 8; c++) {
        sbuf[ns * 256 + j0 + c] = s[c];
        qbuf[ns * 256 + j0 + c] = q[c];
    }
    __syncthreads();
    float ss = 0.f, qq = 0.f;
#pragma unroll
    for (int n2 = 0; n2 < 8; n2++) {
        ss += sbuf[n2 * 256 + t];
        qq += qbuf[n2 * 256 + t];
    }
    atomicAdd(&stats[t], ss);
    atomicAdd(&stats[256 + t], qq);
}

// ---------------- BN apply + ReLU + optional fp8 shadow (v2) --------
// Stats reduction computed ONCE per block into LDS (256 threads x 16 loads)
// instead of per-thread (x8 fewer loads); threads then read their 8 sc/sh
// pairs from LDS. Grid is exactly N_NODES*32/256 -> no early return before
// the barrier.
__global__ __launch_bounds__(256) void k_bn_apply_relu(
        unsigned short* __restrict__ h, const float* __restrict__ stats,
        const float* __restrict__ g, const float* __restrict__ b,
        unsigned char* __restrict__ h8) {
    __shared__ float scs[256], shs[256];
    int t = threadIdx.x;
    {
        const float invn = 1.0f / (float)N_NODES;
        float ssum = 0.f, qsum = 0.f;
#pragma unroll
        for (int s = 0; s < NSHARD; s++) {
            ssum += stats[s * SSTRIDE + t];
            qsum += stats[s * SSTRIDE + 256 + t];
        }
        float mu = ssum * invn;
        float var = qsum * invn - mu * mu;
        float sc = g[t] * rsqrtf(var + BN_EPS);
        scs[t] = sc;
        shs[t] = b[t] - mu * sc;
    }
    __syncthreads();
    int idx = blockIdx.x * 256 + t;
    if (idx >= N_NODES * 32) return;
    int j0 = (idx & 31) * 8;
    float sc[8], sh[8];
#pragma unroll
    for (int k = 0; k < 8; k++) { sc[k] = scs[j0 + k]; sh[k] = shs[j0 + k]; }
    uint4 v = ((uint4*)h)[idx];
    float f0 = fmaxf(bf_lo(v.x) * sc[0] + sh[0], 0.f);
    float f1 = fmaxf(bf_hi(v.x) * sc[1] + sh[1], 0.f);
    float f2 = fmaxf(bf_lo(v.y) * sc[2] + sh[2], 0.f);
    float f3 = fmaxf(bf_hi(v.y) * sc[3] + sh[3], 0.f);
    float f4 = fmaxf(bf_lo(v.z) * sc[4] + sh[4], 0.f);
    float f5 = fmaxf(bf_hi(v.z) * sc[5] + sh[5], 0.f);
    float f6 = fmaxf(bf_lo(v.w) * sc[6] + sh[6], 0.f);
    float f7 = fmaxf(bf_hi(v.w) * sc[7] + sh[7], 0.f);
    uint4 o;
    o.x = (unsigned)f2bf(f0) | ((unsigned)f2bf(f1) << 16);
    o.y = (unsigned)f2bf(f2) | ((unsigned)f2bf(f3) << 16);
    o.z = (unsigned)f2bf(f4) | ((unsigned)f2bf(f5) << 16);
    o.w = (unsigned)f2bf(f6) | ((unsigned)f2bf(f7) << 16);
    ((uint4*)h)[idx] = o;
    if (h8) {
        unsigned pa = __builtin_amdgcn_cvt_pk_fp8_f32(f0, f1, 0u, false);
        pa = __builtin_amdgcn_cvt_pk_fp8_f32(f2, f3, pa, true);
        unsigned pb = __builtin_amdgcn_cvt_pk_fp8_f32(f4, f5, 0u, false);
        pb = __builtin_amdgcn_cvt_pk_fp8_f32(f6, f7, pb, true);
        uint2 o8; o8.x = pa; o8.y = pb;
        ((uint2*)h8)[idx] = o8;
    }
}

// ---------------- fp8 neighbor mean aggregation: one node per 64-lane wave ------
__global__ void k_aggregate_fp8(const unsigned char* __restrict__ h8,
                                const int* __restrict__ deg,
                                const int* __restrict__ sorted_src,
                                unsigned short* __restrict__ agg) {
    int node = (blockIdx.x * blockDim.x + threadIdx.x) >> 6;
    int l = threadIdx.x & 63;
    int ec = l >> 4;        // edge slot 0..3
    int lane = l & 15;      // feature lane
    if (node >= N_NODES) return;
    int beg = node * BCAP;
    int d = deg[node];
    const uint4* h4 = (const uint4*)h8;
    float a[16] = {};
    for (int e = beg + ec; e < beg + d; e += 4) {
        int s = sorted_src[e];
        uint4 v = h4[(size_t)s * 16 + lane];
        floatx2 p;
        p = __builtin_amdgcn_cvt_pk_f32_fp8(v.x, false); a[0] += p.x;  a[1] += p.y;
        p = __builtin_amdgcn_cvt_pk_f32_fp8(v.x, true);  a[2] += p.x;  a[3] += p.y;
        p = __builtin_amdgcn_cvt_pk_f32_fp8(v.y, false); a[4] += p.x;  a[5] += p.y;
        p = __builtin_amdgcn_cvt_pk_f32_fp8(v.y, true);  a[6] += p.x;  a[7] += p.y;
        p = __builtin_amdgcn_cvt_pk_f32_fp8(v.z, false); a[8] += p.x;  a[9] += p.y;
        p = __builtin_amdgcn_cvt_pk_f32_fp8(v.z, true);  a[10] += p.x; a[11] += p.y;
        p = __builtin_amdgcn_cvt_pk_f32_fp8(v.w, false); a[12] += p.x; a[13] += p.y;
        p = __builtin_amdgcn_cvt_pk_f32_fp8(v.w, true);  a[14] += p.x; a[15] += p.y;
    }
#pragma unroll
    for (int i = 0; i < 16; i++) {
        a[i] += __shfl_xor(a[i], 32, 64);
        a[i] += __shfl_xor(a[i], 16, 64);
    }
    if (ec) return;
    float inv = 1.0f / (float)(d > 1 ? d : 1);
    uint4 o0, o1;
    o0.x = (unsigned)f2bf(a[0] * inv)  | ((unsigned)f2bf(a[1] * inv) << 16);
    o0.y = (unsigned)f2bf(a[2] * inv)  | ((unsigned)f2bf(a[3] * inv) << 16);
    o0.z = (unsigned)f2bf(a[4] * inv)  | ((unsigned)f2bf(a[5] * inv) << 16);
    o0.w = (unsigned)f2bf(a[6] * inv)  | ((unsigned)f2bf(a[7] * inv) << 16);
    o1.x = (unsigned)f2bf(a[8] * inv)  | ((unsigned)f2bf(a[9] * inv) << 16);
    o1.y = (unsigned)f2bf(a[10] * inv) | ((unsigned)f2bf(a[11] * inv) << 16);
    o1.z = (unsigned)f2bf(a[12] * inv) | ((unsigned)f2bf(a[13] * inv) << 16);
    o1.w = (unsigned)f2bf(a[14] * inv) | ((unsigned)f2bf(a[15] * inv) << 16);
    ((uint4*)agg)[(size_t)node * 32 + lane * 2] = o0;
    ((uint4*)agg)[(size_t)node * 32 + lane * 2 + 1] = o1;
}

// ---------------- bf16 aggregate-mean ADD into fp32 out: one node per wave ----------
__global__ void k_aggregate_add(const unsigned short* __restrict__ G,
                                const int* __restrict__ deg, const int* __restrict__ sorted_src,
                                float* __restrict__ out) {
    int node = (blockIdx.x * blockDim.x + threadIdx.x) >> 6;
    int l = threadIdx.x & 63;
    int ec = l >> 4;
    int lane = l & 15;
    if (node >= N_NODES) return;
    int beg = node * BCAP;
    int d = deg[node];
    const uint4* h4 = (const uint4*)G;
    float a0 = 0.f, a1 = 0.f, a2 = 0.f, a3 = 0.f, a4 = 0.f, a5 = 0.f, a6 = 0.f, a7 = 0.f;
    for (int e = beg + ec; e < beg + d; e += 4) {
        int s = sorted_src[e];
        uint4 v = h4[(size_t)s * 16 + lane];
        a0 += bf_lo(v.x); a1 += bf_hi(v.x);
        a2 += bf_lo(v.y); a3 += bf_hi(v.y);
        a4 += bf_lo(v.z); a5 += bf_hi(v.z);
        a6 += bf_lo(v.w); a7 += bf_hi(v.w);
    }
    float r[8] = {a0, a1, a2, a3, a4, a5, a6, a7};
#pragma unroll
    for (int i = 0; i < 8; i++) {
        r[i] += __shfl_xor(r[i], 32, 64);
        r[i] += __shfl_xor(r[i], 16, 64);
    }
    if (ec) return;
    float inv = 1.0f / (float)(d > 1 ? d : 1);
    float4* ob = (float4*)(out + (size_t)node * EMB + lane * 8);
    float4 p0 = ob[0], p1 = ob[1];
    p0.x += r[0] * inv; p0.y += r[1] * inv; p0.z += r[2] * inv; p0.w += r[3] * inv;
    p1.x += r[4] * inv; p1.y += r[5] * inv; p1.z += r[6] * inv; p1.w += r[7] * inv;
    ob[0] = p0; ob[1] = p1;
}

#define BK 64

// ---------------- dual-source bf16 MFMA GEMM v3 (layers 1,2) ----------
// [REVERTED from v4 -- R9: privatizing B to registers doubled B traffic
// (wm=0/1 waves share B columns; LDS existed to share it) and uncoalesced
// the loads: 52.7us vs v3's ~40. Restored R7-proven v3.]
// 128x128 tile, 512 threads (8 waves). A,B via global_load_lds w16 into
// double-buffered LDS with XOR involution swizzle (pre-swizzled source +
// swizzled ds_read). Counted s_waitcnt vmcnt(4) + raw s_barrier keeps the
// next tile's loads in flight under the MFMA phase. T5 setprio on MFMA.
#define GEMM_BLKS 784

template <int NCOL, bool STATS>
__global__ __launch_bounds__(512, 4) void k_gemm_mfma(
        const unsigned short* __restrict__ A1, const unsigned short* __restrict__ B1t,
        const unsigned short* __restrict__ A2, const unsigned short* __restrict__ B2t,
        const float* __restrict__ bias, float* __restrict__ stats,
        unsigned short* __restrict__ Cout) {
    int b = blockIdx.x;
    int xcd = b & 7;
    int q = b >> 3;
    int cx = q & 1;
    int pr = (q >> 1) * 8 + xcd;
    int r0 = pr * 128;
    if (r0 >= N_NODES) return;
    int c0 = cx * 128;

    // per row: 64 k-shorts = 8 slots of 16B. phys slot ps holds logical k-slot
    // ls = ps ^ (row&7)  (involution -> same map on stage-source and read).
    __shared__ __attribute__((aligned(16))) unsigned short As[2][128 * 64];  // 2 x 16KB
    __shared__ __attribute__((aligned(16))) unsigned short Bs[2][128 * 64];  // 2 x 16KB

    int t = threadIdx.x;
    int wave = t >> 6, lane = t & 63;
    int wm = wave >> 2, wn = wave & 3;
    int quad = lane >> 4, l15 = lane & 15;

    floatx4 acc[4][2];
#pragma unroll
    for (int i = 0; i < 4; i++)
#pragma unroll
        for (int j = 0; j < 2; j++) acc[i][j] = (floatx4){0.f, 0.f, 0.f, 0.f};

    auto stage = [&](int buf, const unsigned short* __restrict__ A,
                     const unsigned short* __restrict__ B, int k0) {
#pragma unroll
        for (int it = 0; it < 2; it++) {
            int p = it * 512 + t;        // 0..1023 16B-slots
            int row = p >> 3, ps = p & 7;
            int ls = ps ^ (row & 7);
            int rr = r0 + row;
            if (rr >= N_NODES) rr = N_NODES - 1;  // junk; masked in epilogue
            gload_lds16(&A[(size_t)rr * HID + k0 + ls * 8], &As[buf][p * 8]);
        }
#pragma unroll
        for (int it = 0; it < 2; it++) {
            int p = it * 512 + t;
            int row = p >> 3, ps = p & 7;
            int ls = ps ^ (row & 7);
            gload_lds16(&B[(size_t)(c0 + row) * HID + k0 + ls * 8], &Bs[buf][p * 8]);
        }
    };

    stage(0, A1, B1t, 0);  // 4 loads/thread in flight

    int cur = 0;
#pragma unroll
    for (int ph = 0; ph < 8; ph++) {
        if (ph < 7) {
            int np = ph + 1;
            stage(cur ^ 1, (np >= 4) ? A2 : A1, (np >= 4) ? B2t : B1t, (np & 3) * BK);
            // wait only the CURRENT buffer's 4 loads (oldest); keep next 4 in flight
            asm volatile("s_waitcnt vmcnt(4)\n\ts_barrier" ::: "memory");
        } else {
            asm volatile("s_waitcnt vmcnt(0)\n\ts_barrier" ::: "memory");
        }
#pragma unroll
        for (int kc = 0; kc < 2; kc++) {
            short8 a[4], bfr[2];
            int ls = kc * 4 + quad;
#pragma unroll
            for (int i = 0; i < 4; i++) {
                int arow = wm * 64 + i * 16 + l15;
                int ps = ls ^ (arow & 7);
                a[i] = *(const short8*)&As[cur][arow * 64 + ps * 8];
            }
#pragma unroll
            for (int j = 0; j < 2; j++) {
                int brow = wn * 32 + j * 16 + l15;
                int ps = ls ^ (brow & 7);
                bfr[j] = *(const short8*)&Bs[cur][brow * 64 + ps * 8];
            }
            __builtin_amdgcn_s_setprio(1);
#pragma unroll
            for (int i = 0; i < 4; i++)
#pragma unroll
                for (int j = 0; j < 2; j++)
                    acc[i][j] = __builtin_amdgcn_mfma_f32_16x16x32_bf16(a[i], bfr[j], acc[i][j], 0, 0, 0);
            __builtin_amdgcn_s_setprio(0);
        }
        // all waves' reads of buf[cur] done before next phase's stage overwrites it
        asm volatile("s_barrier" ::: "memory");
        cur ^= 1;
    }

    float bv[2];
#pragma unroll
    for (int j = 0; j < 2; j++) bv[j] = bias[c0 + wn * 32 + j * 16 + l15];

    float s_part[2] = {0.f, 0.f};
    float q_part[2] = {0.f, 0.f};

#pragma unroll
    for (int i = 0; i < 4; i++) {
#pragma unroll
        for (int r = 0; r < 4; r++) {
            int m = r0 + wm * 64 + i * 16 + quad * 4 + r;
            if (m >= N_NODES) continue;
#pragma unroll
            for (int j = 0; j < 2; j++) {
                int n = c0 + wn * 32 + j * 16 + l15;
                float v = acc[i][j][r] + bv[j];
                if (STATS) { s_part[j] += v; q_part[j] += v * v; }
                Cout[(size_t)m * NCOL + n] = f2bf(v);
            }
        }
    }

    if (STATS) {
        float* sred = (float*)As;
        __syncthreads();
        if (t < 256) sred[t] = 0.f;
        __syncthreads();
#pragma unroll
        for (int j = 0; j < 2; j++) {
            int cl = wn * 32 + j * 16 + l15;
            atomicAdd(&sred[cl], s_part[j]);
            atomicAdd(&sred[128 + cl], q_part[j]);
        }
        __syncthreads();
        if (t < 128) {
            int base = (pr & (NSHARD - 1)) * SSTRIDE;
            atomicAdd(&stats[base + c0 + t], sred[t]);
            atomicAdd(&stats[base + 256 + c0 + t], sred[128 + t]);
        }
    }
}

// ---------------- layer-3 dual-OUTPUT GEMM v2: pipelined, fused 256-row B^T ----------
#define L3_BLKS 784

__global__ __launch_bounds__(512, 4) void k_gemm_l3_dual(
        const unsigned short* __restrict__ A, const unsigned short* __restrict__ Bt,
        const float* __restrict__ stats,
        const float* __restrict__ g, const float* __restrict__ be,
        const float* __restrict__ bl3, unsigned short* __restrict__ G,
        float* __restrict__ P) {
    int b = blockIdx.x;
    int xcd = b & 7;
    int q = b >> 3;
    int cx = q & 1;
    int pr = (q >> 1) * 8 + xcd;
    int r0 = pr * 128;
    if (r0 >= N_NODES) return;
    int c0 = cx * 128;

    __shared__ __attribute__((aligned(16))) unsigned short As[128 * 64];      // 16KB
    __shared__ __attribute__((aligned(16))) unsigned short Bs[2][128 * 64];   // 32KB
    __shared__ float scs[256], shs[256];

    int t = threadIdx.x;
    if (t < 256) {
        const float invn = 1.0f / (float)N_NODES;
        float ssum = 0.f, qsum = 0.f;
#pragma unroll
        for (int s = 0; s < NSHARD; s++) {
            ssum += stats[s * SSTRIDE + t];
            qsum += stats[s * SSTRIDE + 256 + t];
        }
        float mu = ssum * invn;
        float var = qsum * invn - mu * mu;
        float sc = g[t] * rsqrtf(var + BN_EPS);
        scs[t] = sc;
        shs[t] = be[t] - mu * sc;
    }
    __syncthreads();  // drains all vm; clean vmcnt baseline for the pipeline

    int wave = t >> 6, lane = t & 63;
    int wm = wave >> 2, wn = wave & 3;
    int quad = lane >> 4, l15 = lane & 15;

    floatx4 acc[4][2];
#pragma unroll
    for (int i = 0; i < 4; i++)
#pragma unroll
        for (int j = 0; j < 2; j++) acc[i][j] = (floatx4){0.f, 0.f, 0.f, 0.f};

    // thread's two staging slots (same for A and B paths)
    int p0_ = t, p1_ = 512 + t;
    int row0 = p0_ >> 3, ps0 = p0_ & 7, ls0 = ps0 ^ (row0 & 7);
    int row1 = p1_ >> 3, ps1 = p1_ & 7, ls1 = ps1 ^ (row1 & 7);
    int ar0 = r0 + row0; if (ar0 >= N_NODES) ar0 = N_NODES - 1;
    int ar1 = r0 + row1; if (ar1 >= N_NODES) ar1 = N_NODES - 1;

    auto stageB = [&](int buf, int k0) {
        gload_lds16(&Bt[(size_t)(c0 + row0) * HID + k0 + ls0 * 8], &Bs[buf][p0_ * 8]);
        gload_lds16(&Bt[(size_t)(c0 + row1) * HID + k0 + ls1 * 8], &Bs[buf][p1_ * 8]);
    };
    auto issueA = [&](int k0, uint4& v0, uint4& v1) {
        v0 = *(const uint4*)&A[(size_t)ar0 * HID + k0 + ls0 * 8];
        v1 = *(const uint4*)&A[(size_t)ar1 * HID + k0 + ls1 * 8];
    };
    auto xform = [&](uint4 vv, int cb) -> uint4 {
        float4 s0 = *(float4*)&scs[cb], s1 = *(float4*)&scs[cb + 4];
        float4 h0 = *(float4*)&shs[cb], h1 = *(float4*)&shs[cb + 4];
        float f0 = fmaxf(bf_lo(vv.x) * s0.x + h0.x, 0.f);
        float f1 = fmaxf(bf_hi(vv.x) * s0.y + h0.y, 0.f);
        float f2 = fmaxf(bf_lo(vv.y) * s0.z + h0.z, 0.f);
        float f3 = fmaxf(bf_hi(vv.y) * s0.w + h0.w, 0.f);
        float f4 = fmaxf(bf_lo(vv.z) * s1.x + h1.x, 0.f);
        float f5 = fmaxf(bf_hi(vv.z) * s1.y + h1.y, 0.f);
        float f6 = fmaxf(bf_lo(vv.w) * s1.z + h1.z, 0.f);
        float f7 = fmaxf(bf_hi(vv.w) * s1.w + h1.w, 0.f);
        uint4 ov;
        ov.x = (unsigned)f2bf(f0) | ((unsigned)f2bf(f1) << 16);
        ov.y = (unsigned)f2bf(f2) | ((unsigned)f2bf(f3) << 16);
        ov.z = (unsigned)f2bf(f4) | ((unsigned)f2bf(f5) << 16);
        ov.w = (unsigned)f2bf(f6) | ((unsigned)f2bf(f7) << 16);
        return ov;
    };

    uint4 va0, va1, vb0, vb1;
    stageB(0, 0);        // B(0): 2 DMA
    issueA(0, va0, va1); // A(0): 2 reg loads (order: B then A)

    int cur = 0;
#pragma unroll
    for (int ph = 0; ph < 4; ph++) {
        if (ph < 3) {
            stageB(cur ^ 1, (ph + 1) * BK);                    // B(ph+1): 2 DMA newest
            asm volatile("s_waitcnt vmcnt(2)" ::: "memory");   // drains B(ph), A(ph)
        } else {
            asm volatile("s_waitcnt vmcnt(0)" ::: "memory");
        }
        // transform A(ph) -> As (phys slots, XOR-swizzled logical source)
        *(uint4*)&As[p0_ * 8] = xform(va0, ph * BK + ls0 * 8);
        *(uint4*)&As[p1_ * 8] = xform(va1, ph * BK + ls1 * 8);
        asm volatile("s_waitcnt lgkmcnt(0)\n\ts_barrier" ::: "memory");
        if (ph < 3) issueA((ph + 1) * BK, vb0, vb1);  // hides under MFMA below
#pragma unroll
        for (int kc = 0; kc < 2; kc++) {
            short8 a[4], bfr[2];
            int ls = kc * 4 + quad;
#pragma unroll
            for (int i = 0; i < 4; i++) {
                int arow = wm * 64 + i * 16 + l15;
                int ps = ls ^ (arow & 7);
                a[i] = *(const short8*)&As[arow * 64 + ps * 8];
            }
#pragma unroll
            for (int j = 0; j < 2; j++) {
                int brow = wn * 32 + j * 16 + l15;
                int ps = ls ^ (brow & 7);
                bfr[j] = *(const short8*)&Bs[cur][brow * 64 + ps * 8];
            }
            __builtin_amdgcn_s_setprio(1);
#pragma unroll
            for (int i = 0; i < 4; i++)
#pragma unroll
                for (int j = 0; j < 2; j++)
                    acc[i][j] = __builtin_amdgcn_mfma_f32_16x16x32_bf16(a[i], bfr[j], acc[i][j], 0, 0, 0);
            __builtin_amdgcn_s_setprio(0);
        }
        asm volatile("s_barrier" ::: "memory");
        cur ^= 1;
        va0 = vb0; va1 = vb1;
    }

    float bv[2];
#pragma unroll
    for (int j = 0; j < 2; j++) bv[j] = bl3[wn * 32 + j * 16 + l15];

#pragma unroll
    for (int i = 0; i < 4; i++) {
#pragma unroll
        for (int r = 0; r < 4; r++) {
            int m = r0 + wm * 64 + i * 16 + quad * 4 + r;
            if (m >= N_NODES) continue;
#pragma unroll
            for (int j = 0; j < 2; j++) {
                int n = wn * 32 + j * 16 + l15;
                if (cx == 0) G[(size_t)m * EMB + n] = f2bf(acc[i][j][r]);
                else         P[(size_t)m * EMB + n] = acc[i][j][r] + bv[j];
            }
        }
    }
}

extern "C" void kernel_launch(void* const* d_in, const int* in_sizes, int n_in,
                              void* d_out, int out_size, void* d_ws, size_t ws_size,
                              hipStream_t stream) {
    const float* x    = (const float*)d_in[0];
    const int*   ei   = (const int*)d_in[1];
    const float* w_in = (const float*)d_in[2];
    const float* b_in = (const float*)d_in[3];
    const float* g_in = (const float*)d_in[4];
    const float* be_in= (const float*)d_in[5];
    const float* wl1  = (const float*)d_in[6];
    const float* bl1  = (const float*)d_in[7];
    const float* wr1  = (const float*)d_in[8];
    const float* g1   = (const float*)d_in[9];
    const float* be1  = (const float*)d_in[10];
    const float* wl2  = (const float*)d_in[11];
    const float* bl2  = (const float*)d_in[12];
    const float* wr2  = (const float*)d_in[13];
    const float* g2   = (const float*)d_in[14];
    const float* be2  = (const float*)d_in[15];
    const float* wl3  = (const float*)d_in[16];
    const float* bl3  = (const float*)d_in[17];
    const float* wr3  = (const float*)d_in[18];
    float* out = (float*)d_out;

    char* p = (char*)d_ws;
    auto alloc = [&](size_t bytes) -> void* {
        void* r = (void*)p;
        p += (bytes + 255) & ~(size_t)255;
        return r;
    };
    // zero-region: fill_pos + 3 sharded stats buffers (contiguous)
    int*   fill_pos = (int*)alloc((size_t)N_NODES * 4);
    float* stats0 = (float*)alloc((size_t)NSHARD * SSTRIDE * 4);
    float* stats1 = (float*)alloc((size_t)NSHARD * SSTRIDE * 4);
    float* stats2 = (float*)alloc((size_t)NSHARD * SSTRIDE * 4);
    size_t zlen = (size_t)((char*)stats2 + NSHARD * SSTRIDE * 4 - (char*)fill_pos);

    unsigned short* bufA = (unsigned short*)alloc((size_t)N_NODES * HID * 2);
    unsigned short* bufB = (unsigned short*)alloc((size_t)N_NODES * HID * 2);
    unsigned short* bufC = (unsigned short*)alloc((size_t)N_NODES * HID * 2);
    unsigned char*  h8   = (unsigned char*)alloc((size_t)N_NODES * HID);
    unsigned short* wl1t = (unsigned short*)alloc((size_t)HID * HID * 2);
    unsigned short* wr1t = (unsigned short*)alloc((size_t)HID * HID * 2);
    unsigned short* wl2t = (unsigned short*)alloc((size_t)HID * HID * 2);
    unsigned short* wr2t = (unsigned short*)alloc((size_t)HID * HID * 2);
    unsigned short* wl3t = (unsigned short*)alloc((size_t)EMB * HID * 2);  // contiguous with wr3t:
    unsigned short* wr3t = (unsigned short*)alloc((size_t)EMB * HID * 2);  // fused 256-row B^T for l3
    int*   sorted_src = (int*)alloc((size_t)N_NODES * BCAP * 4);           // 12.8 MB buckets
    (void)wr3t;

    const int* e_src = ei;
    const int* e_dst = ei + N_EDGES;

    hipMemsetAsync(fill_pos, 0, zlen, stream);
    k_scatter_bucket<<<SCAT_BLKS, 256, 0, stream>>>(e_src, e_dst, fill_pos, sorted_src);
    k_wconv_ip<<<WCONV_BLKS + IP_BLOCKS, 256, 0, stream>>>(
        wl1, wr1, wl2, wr2, wl3, wr3, wl1t, wr1t, wl2t, wr2t, wl3t, wr3t,
        x, w_in, b_in, bufA, stats0);
    k_bn_apply_relu<<<(N_NODES * 32 + 255) / 256, 256, 0, stream>>>(bufA, stats0, g_in, be_in, h8);

    int agg_blocks = ((size_t)N_NODES * 64 + 255) / 256;  // 12500

    // SAGE layer 1
    k_aggregate_fp8<<<agg_blocks, 256, 0, stream>>>(h8, fill_pos, sorted_src, bufC);
    k_gemm_mfma<HID, true><<<GEMM_BLKS, 512, 0, stream>>>(bufC, wl1t, bufA, wr1t, bl1, stats1, bufB);
    k_bn_apply_relu<<<(N_NODES * 32 + 255) / 256, 256, 0, stream>>>(bufB, stats1, g1, be1, h8);

    // SAGE layer 2 (raw h2 + stats2; BN deferred into layer-3 GEMM)
    k_aggregate_fp8<<<agg_blocks, 256, 0, stream>>>(h8, fill_pos, sorted_src, bufC);
    k_gemm_mfma<HID, true><<<GEMM_BLKS, 512, 0, stream>>>(bufC, wl2t, bufB, wr2t, bl2, stats2, bufA);

    // layer-3 dual GEMM with fused BN (fused B^T = wl3t||wr3t), then out += mean of G
    k_gemm_l3_dual<<<L3_BLKS, 512, 0, stream>>>(
        bufA, wl3t, stats2, g2, be2, bl3, bufB, out);
    k_aggregate_add<<<agg_blocks, 256, 0, stream>>>(bufB, fill_pos, sorted_src, out);
}